// Round 9
// baseline (245.729 us; speedup 1.0000x reference)
//
#include <hip/hip_runtime.h>
#include <hip/hip_bf16.h>

#define NN 256
#define CC 128

typedef __attribute__((ext_vector_type(8))) short bf16x8;
typedef __attribute__((ext_vector_type(4))) short bf16x4;
typedef __attribute__((ext_vector_type(4))) float f32x4;

static __device__ __forceinline__ short f2bf(float f) {
  union { float f; unsigned u; } un; un.f = f;
  unsigned r = un.u + 0x7fff + ((un.u >> 16) & 1);
  return (short)(r >> 16);
}
static __device__ __forceinline__ float bf2f(short s) {
  union { unsigned u; float f; } un;
  un.u = ((unsigned)(unsigned short)s) << 16;
  return un.f;
}

// ---------------- Kernel P: pre-pack weights to bf16 A-fragment layout ----------
// wpk[w][nt][kc][lane][8]: 16B chunk = W[nt*16 + (lane&15)][kc*32 + (lane>>4)*8 ..+7]
// w: 0=q 1=k 2=v 3=g 4=o. grid 40 x 256 (10240 chunks).
__global__ void prep_kernel(const float* __restrict__ Wq, const float* __restrict__ Wk,
                            const float* __restrict__ Wv, const float* __restrict__ Wg,
                            const float* __restrict__ Wo, short* __restrict__ wpk)
{
  const int c = blockIdx.x * 256 + threadIdx.x;   // 0..10239
  const int w = c >> 11;
  const int rem = c & 2047;
  const int nt = rem >> 8;
  const int kc = (rem >> 6) & 3;
  const int lane = rem & 63;
  const float* W = (w == 0) ? Wq : (w == 1) ? Wk : (w == 2) ? Wv : (w == 3) ? Wg : Wo;
  const int row = nt * 16 + (lane & 15);
  const int col = kc * 32 + (lane >> 4) * 8;
  const float* src = W + row * CC + col;
  bf16x8 b;
  #pragma unroll
  for (int j = 0; j < 8; ++j) b[j] = f2bf(src[j]);
  *(bf16x8*)(wpk + (size_t)c * 8) = b;
}

// ---------------- Fused kernel: block per i (grid 256, 512 threads = 8 waves) ----
// LDS (exact 160 KiB):
//   Ksl  [256 kpos][128 ch]  bf16, XOR-swizzled:  idx = kp*128 + (ch ^ ((kp&7)<<3))
//   Vsl  [128 ch][256 kpos]  bf16, XOR-swizzled:  idx = ch*256 + (kp ^ ((ch&7)<<3))
//   P    8 waves x [16 q][128 kp-half] bf16:      idx = q*128 + (kp_l ^ ((q&7)<<3))
// Phase 1: wave-pair per projection (q,k,v,gate); K,V^T -> LDS; Q,gate -> global bf16.
// Phase 2: wave = (head, q-half); QK^T swapped (lane owns q-row t16's scores);
//          softmax in-lane + shfl(16,32); PV in two kpos-halves of 128 through P-LDS.
// Phase 3: Wo staged into freed K-slot; gate*aout @ Wo^T + pair + LayerNorm.
__global__ __launch_bounds__(512, 2) void fused_kernel(
    const float* __restrict__ pair, const short* __restrict__ wpk,
    const float* __restrict__ bq, const float* __restrict__ bk,
    const float* __restrict__ bv, const float* __restrict__ bg,
    const float* __restrict__ bo, const float* __restrict__ gamma,
    const float* __restrict__ beta,
    short* __restrict__ Qg, short* __restrict__ Gg, short* __restrict__ Ag,
    float* __restrict__ out)
{
  __shared__ short lds[81920];     // 163840 B = 160 KiB exact
  short* Ksl = lds;                // 32768 shorts
  short* Vsl = lds + 32768;        // 32768 shorts

  const int i    = blockIdx.x;
  const int tid  = threadIdx.x;
  const int wid  = tid >> 6, lane = tid & 63;
  const int g    = lane >> 4, t16 = lane & 15;
  const size_t prow = (size_t)i * NN * CC;   // element base of this i-row block

  // ================= Phase 1: projections =================
  {
    const int gm = wid >> 1;        // 0=q 1=k 2=v 3=gate
    const int rh = wid & 1;         // row half
    const short* wsrc = wpk + (size_t)gm * 16384;
    bf16x8 wf[8][4];
    #pragma unroll
    for (int nt = 0; nt < 8; ++nt)
      #pragma unroll
      for (int kc = 0; kc < 4; ++kc)
        wf[nt][kc] = *(const bf16x8*)(wsrc + ((nt*4 + kc)*64 + lane)*8);
    const float* bias = (gm == 0) ? bq : (gm == 1) ? bk : (gm == 2) ? bv : bg;

    #pragma unroll 1
    for (int mc = 0; mc < 8; ++mc) {
      const int m = rh*128 + mc*16 + t16;     // kpos / row index
      bf16x8 pf[4];
      #pragma unroll
      for (int kc = 0; kc < 4; ++kc) {
        const float* p = pair + prow + (size_t)m*CC + kc*32 + g*8;
        bf16x8 a;
        #pragma unroll
        for (int j = 0; j < 8; ++j) a[j] = f2bf(p[j]);
        pf[kc] = a;
      }
      f32x4 acc[8];
      #pragma unroll
      for (int nt = 0; nt < 8; ++nt) acc[nt] = f32x4{0.f,0.f,0.f,0.f};
      #pragma unroll
      for (int kc = 0; kc < 4; ++kc)
        #pragma unroll
        for (int nt = 0; nt < 8; ++nt)
          acc[nt] = __builtin_amdgcn_mfma_f32_16x16x32_bf16(wf[nt][kc], pf[kc], acc[nt], 0, 0, 0);

      // D[n][m]: lane owns cols n = nt*16 + g*4 + r of row m
      if (gm == 0) {            // Q -> global [row][C]
        #pragma unroll
        for (int nt = 0; nt < 8; ++nt) {
          f32x4 b4 = *(const f32x4*)(bias + nt*16 + g*4);
          bf16x4 pk;
          #pragma unroll
          for (int r = 0; r < 4; ++r) pk[r] = f2bf(acc[nt][r] + b4[r]);
          *(bf16x4*)(Qg + prow + (size_t)m*CC + nt*16 + g*4) = pk;
        }
      } else if (gm == 1) {     // K -> LDS [kpos][ch] swizzled
        #pragma unroll
        for (int nt = 0; nt < 8; ++nt) {
          f32x4 b4 = *(const f32x4*)(bias + nt*16 + g*4);
          bf16x4 pk;
          #pragma unroll
          for (int r = 0; r < 4; ++r) pk[r] = f2bf(acc[nt][r] + b4[r]);
          *(bf16x4*)&Ksl[m*128 + ((nt*16 + g*4) ^ ((m & 7) << 3))] = pk;
        }
      } else if (gm == 2) {     // V -> LDS transposed [ch][kpos] swizzled
        #pragma unroll
        for (int nt = 0; nt < 8; ++nt) {
          f32x4 b4 = *(const f32x4*)(bias + nt*16 + g*4);
          #pragma unroll
          for (int r = 0; r < 4; ++r) {
            const int ch = nt*16 + g*4 + r;
            Vsl[ch*256 + (m ^ ((ch & 7) << 3))] = f2bf(acc[nt][r] + b4[r]);
          }
        }
      } else {                  // gate -> sigmoid -> global [row][C]
        #pragma unroll
        for (int nt = 0; nt < 8; ++nt) {
          f32x4 b4 = *(const f32x4*)(bias + nt*16 + g*4);
          bf16x4 pk;
          #pragma unroll
          for (int r = 0; r < 4; ++r) {
            float v = acc[nt][r] + b4[r];
            pk[r] = f2bf(1.f / (1.f + __expf(-v)));
          }
          *(bf16x4*)(Gg + prow + (size_t)m*CC + nt*16 + g*4) = pk;
        }
      }
    }
  }
  __syncthreads();

  // ================= Phase 2: attention =================
  {
    const int h  = wid >> 1;
    const int qh = wid & 1;
    short* Pw = lds + 65536 + wid*2048;   // [16][128] swizzled, per kpos-half

    bf16x8 qf[8];                          // prefetch all Q B-frags for this wave
    #pragma unroll
    for (int cc = 0; cc < 8; ++cc)
      qf[cc] = *(const bf16x8*)(Qg + prow + (size_t)(qh*128 + cc*16 + t16)*CC + h*32 + g*8);

    const float cs = 0.17677669529663689f * 1.4426950408889634f; // scale * log2(e)
    const int swzP = (t16 & 7) << 3;
    const int ch0 = h*32 + t16, ch1 = ch0 + 16;
    const int swzV = (ch0 & 7) << 3;       // ch1&7 == ch0&7

    #pragma unroll 1
    for (int cc = 0; cc < 8; ++cc) {
      const int q0 = qh*128 + cc*16;

      f32x4 s[16];
      #pragma unroll
      for (int t = 0; t < 16; ++t) {
        const int row = t*16 + t16;
        bf16x8 kf = *(const bf16x8*)&Ksl[row*128 + ((h*32 + g*8) ^ ((t16 & 7) << 3))];
        s[t] = __builtin_amdgcn_mfma_f32_16x16x32_bf16(kf, qf[cc], f32x4{0.f,0.f,0.f,0.f}, 0, 0, 0);
      }

      // softmax for q-row q0+t16: 64 in-lane scores + reduce across g (lanes ±16, ±32)
      f32x4 m4 = s[0];
      #pragma unroll
      for (int t = 1; t < 16; ++t)
        #pragma unroll
        for (int r = 0; r < 4; ++r) m4[r] = fmaxf(m4[r], s[t][r]);
      float mx = fmaxf(fmaxf(m4[0], m4[1]), fmaxf(m4[2], m4[3]));
      mx = fmaxf(mx, __shfl_xor(mx, 16));
      mx = fmaxf(mx, __shfl_xor(mx, 32));

      f32x4 s4 = f32x4{0.f,0.f,0.f,0.f};
      #pragma unroll
      for (int t = 0; t < 16; ++t) {
        f32x4 v = s[t];
        #pragma unroll
        for (int r = 0; r < 4; ++r) { v[r] = exp2f((v[r] - mx) * cs); s4[r] += v[r]; }
        s[t] = v;
      }
      float sum = (s4[0] + s4[1]) + (s4[2] + s4[3]);
      sum += __shfl_xor(sum, 16);
      sum += __shfl_xor(sum, 32);
      const float sm = 1.f / sum;

      f32x4 o0 = f32x4{0.f,0.f,0.f,0.f};
      f32x4 o1 = f32x4{0.f,0.f,0.f,0.f};
      #pragma unroll
      for (int half = 0; half < 2; ++half) {
        // WAR: previous P reads (prev half / prev chunk) must complete first
        asm volatile("s_waitcnt lgkmcnt(0)" ::: "memory");
        #pragma unroll
        for (int tt = 0; tt < 8; ++tt) {
          const int t = half*8 + tt;
          bf16x4 pk;
          #pragma unroll
          for (int r = 0; r < 4; ++r) pk[r] = f2bf(s[t][r]);
          *(bf16x4*)&Pw[t16*128 + ((tt*16 + g*4) ^ swzP)] = pk;
        }
        asm volatile("s_waitcnt lgkmcnt(0)" ::: "memory"); // writes land before reads

        bf16x8 pa[4];
        #pragma unroll
        for (int kc = 0; kc < 4; ++kc)
          pa[kc] = *(const bf16x8*)&Pw[t16*128 + ((kc*32 + g*8) ^ swzP)];

        #pragma unroll
        for (int kc = 0; kc < 4; ++kc) {
          const int kb = half*128 + kc*32 + g*8;
          bf16x8 v0 = *(const bf16x8*)&Vsl[ch0*256 + (kb ^ swzV)];
          bf16x8 v1 = *(const bf16x8*)&Vsl[ch1*256 + (kb ^ swzV)];
          o0 = __builtin_amdgcn_mfma_f32_16x16x32_bf16(v0, pa[kc], o0, 0, 0, 0);
          o1 = __builtin_amdgcn_mfma_f32_16x16x32_bf16(v1, pa[kc], o1, 0, 0, 0);
        }
      }

      // D[ch][q]: lane owns 4 consecutive ch for its own q-row (sm in-lane)
      const size_t ob = prow + (size_t)(q0 + t16)*CC + h*32;
      bf16x4 pk0, pk1;
      #pragma unroll
      for (int r = 0; r < 4; ++r) { pk0[r] = f2bf(o0[r] * sm); pk1[r] = f2bf(o1[r] * sm); }
      *(bf16x4*)(Ag + ob + g*4)      = pk0;
      *(bf16x4*)(Ag + ob + 16 + g*4) = pk1;
    }
  }
  __syncthreads();

  // ================= Phase 3: out projection + residual + LN =================
  { // stage prepacked Wo into freed K-slot (linear chunks)
    #pragma unroll
    for (int it = 0; it < 4; ++it) {
      const int c = it*512 + tid;
      *(bf16x8*)&lds[c*8] = *(const bf16x8*)(wpk + 4*16384 + (size_t)c*8);
    }
  }
  __syncthreads();
  {
    #pragma unroll 1
    for (int mc = 0; mc < 2; ++mc) {
      const int m = wid*32 + mc*16 + t16;
      const size_t rowoff = prow + (size_t)m * CC;

      bf16x8 xf[4];
      #pragma unroll
      for (int kc = 0; kc < 4; ++kc) {
        bf16x8 a8 = *(const bf16x8*)(Ag + rowoff + kc*32 + g*8);
        bf16x8 g8 = *(const bf16x8*)(Gg + rowoff + kc*32 + g*8);
        bf16x8 o;
        #pragma unroll
        for (int j = 0; j < 8; ++j) o[j] = f2bf(bf2f(a8[j]) * bf2f(g8[j]));
        xf[kc] = o;
      }

      f32x4 acc[8];
      #pragma unroll
      for (int nt = 0; nt < 8; ++nt) acc[nt] = f32x4{0.f,0.f,0.f,0.f};
      #pragma unroll
      for (int kc = 0; kc < 4; ++kc)
        #pragma unroll
        for (int nt = 0; nt < 8; ++nt) {
          bf16x8 wfr = *(const bf16x8*)&lds[((nt*4 + kc)*64 + lane)*8];
          acc[nt] = __builtin_amdgcn_mfma_f32_16x16x32_bf16(wfr, xf[kc], acc[nt], 0, 0, 0);
        }

      float val[8][4];
      #pragma unroll
      for (int nt = 0; nt < 8; ++nt) {
        f32x4 b4 = *(const f32x4*)(bo + nt*16 + g*4);
        f32x4 p4 = *(const f32x4*)(pair + rowoff + nt*16 + g*4);
        #pragma unroll
        for (int r = 0; r < 4; ++r) val[nt][r] = acc[nt][r] + b4[r] + p4[r];
      }
      float sum = 0.f;
      #pragma unroll
      for (int nt = 0; nt < 8; ++nt)
        #pragma unroll
        for (int r = 0; r < 4; ++r) sum += val[nt][r];
      sum += __shfl_xor(sum, 16); sum += __shfl_xor(sum, 32);
      const float mu = sum * (1.f/128.f);
      float sq = 0.f;
      #pragma unroll
      for (int nt = 0; nt < 8; ++nt)
        #pragma unroll
        for (int r = 0; r < 4; ++r) { float d = val[nt][r] - mu; sq += d*d; }
      sq += __shfl_xor(sq, 16); sq += __shfl_xor(sq, 32);
      const float rstd = rsqrtf(sq * (1.f/128.f) + 1e-5f);

      #pragma unroll
      for (int nt = 0; nt < 8; ++nt) {
        f32x4 g4 = *(const f32x4*)(gamma + nt*16 + g*4);
        f32x4 b4 = *(const f32x4*)(beta  + nt*16 + g*4);
        f32x4 o4;
        #pragma unroll
        for (int r = 0; r < 4; ++r) o4[r] = (val[nt][r] - mu) * rstd * g4[r] + b4[r];
        *(f32x4*)(out + rowoff + nt*16 + g*4) = o4;
      }
    }
  }
}

extern "C" void kernel_launch(void* const* d_in, const int* in_sizes, int n_in,
                              void* d_out, int out_size, void* d_ws, size_t ws_size,
                              hipStream_t stream) {
  const float* pair  = (const float*)d_in[0];
  const float* Wq    = (const float*)d_in[1];
  const float* bq    = (const float*)d_in[2];
  const float* Wk    = (const float*)d_in[3];
  const float* bk    = (const float*)d_in[4];
  const float* Wv    = (const float*)d_in[5];
  const float* bv    = (const float*)d_in[6];
  const float* Wg    = (const float*)d_in[7];
  const float* bg    = (const float*)d_in[8];
  const float* Wo    = (const float*)d_in[9];
  const float* bo    = (const float*)d_in[10];
  const float* gamma = (const float*)d_in[11];
  const float* beta  = (const float*)d_in[12];
  float* out = (float*)d_out;

  short* wpk  = (short*)d_ws;            // 5 * 16384 bf16, prepacked weights
  short* q_ws = wpk + 81920;             // [m][C] bf16
  short* g_ws = q_ws + 8388608;          // [m][C] bf16 (sigmoid applied)
  short* a_ws = g_ws + 8388608;          // [m][C] bf16 attention out

  hipLaunchKernelGGL(prep_kernel, dim3(40), dim3(256), 0, stream,
                     Wq, Wk, Wv, Wg, Wo, wpk);
  hipLaunchKernelGGL(fused_kernel, dim3(256), dim3(512), 0, stream,
                     pair, wpk, bq, bk, bv, bg, bo, gamma, beta,
                     q_ws, g_ws, a_ws, out);
}

// Round 12
// 198.409 us; speedup vs baseline: 1.2385x; 1.2385x over previous
//
#include <hip/hip_runtime.h>
#include <hip/hip_bf16.h>

#define NN 256
#define CC 128

typedef __attribute__((ext_vector_type(8))) short bf16x8;
typedef __attribute__((ext_vector_type(4))) short bf16x4;
typedef __attribute__((ext_vector_type(4))) float f32x4;

static __device__ __forceinline__ short f2bf(float f) {
  union { float f; unsigned u; } un; un.f = f;
  unsigned r = un.u + 0x7fff + ((un.u >> 16) & 1);
  return (short)(r >> 16);
}
static __device__ __forceinline__ float bf2f(short s) {
  union { unsigned u; float f; } un;
  un.u = ((unsigned)(unsigned short)s) << 16;
  return un.f;
}

// ---------------- Kernel P: pre-pack weights to bf16 A-fragment layout ----------
__global__ void prep_kernel(const float* __restrict__ Wq, const float* __restrict__ Wk,
                            const float* __restrict__ Wv, const float* __restrict__ Wg,
                            const float* __restrict__ Wo, short* __restrict__ wpk)
{
  const int c = blockIdx.x * 256 + threadIdx.x;   // 0..10239
  const int w = c >> 11;
  const int rem = c & 2047;
  const int nt = rem >> 8;
  const int kc = (rem >> 6) & 3;
  const int lane = rem & 63;
  const float* W = (w == 0) ? Wq : (w == 1) ? Wk : (w == 2) ? Wv : (w == 3) ? Wg : Wo;
  const int row = nt * 16 + (lane & 15);
  const int col = kc * 32 + (lane >> 4) * 8;
  const float* src = W + row * CC + col;
  bf16x8 b;
  #pragma unroll
  for (int j = 0; j < 8; ++j) b[j] = f2bf(src[j]);
  *(bf16x8*)(wpk + (size_t)c * 8) = b;
}

// ---------------- Kernel A: projections, wave = projection, 64 rows/block -------
// grid 1024, block 256 (4 waves). Raw-f32 prefetch double-buffer across m-iters.
// launch_bounds(256,2): 256-VGPR budget so wf[8][4] (128 VGPR) stays resident.
__global__ __launch_bounds__(256, 2) void proj_kernel(
    const float* __restrict__ pair, const short* __restrict__ wpk,
    const float* __restrict__ bq, const float* __restrict__ bk,
    const float* __restrict__ bv, const float* __restrict__ bg,
    short* __restrict__ qo, short* __restrict__ ko,
    short* __restrict__ vo, short* __restrict__ go)
{
  const int wid  = threadIdx.x >> 6;
  const int lane = threadIdx.x & 63;
  const int g    = lane >> 4;
  const int t16  = lane & 15;

  const short* wsrc = wpk + (size_t)wid * 16384;
  bf16x8 wf[8][4];
  #pragma unroll
  for (int nt = 0; nt < 8; ++nt)
    #pragma unroll
    for (int kc = 0; kc < 4; ++kc)
      wf[nt][kc] = *(const bf16x8*)(wsrc + ((nt*4 + kc)*64 + lane)*8);

  const float* bias = (wid == 0) ? bq : (wid == 1) ? bk : (wid == 2) ? bv : bg;
  f32x4 bcol[8];
  #pragma unroll
  for (int nt = 0; nt < 8; ++nt) bcol[nt] = *(const f32x4*)(bias + nt*16 + g*4);

  short* outp = (wid == 0) ? qo : (wid == 1) ? ko : (wid == 2) ? vo : go;
  const int row0 = blockIdx.x * 64;

  // prologue: raw loads for iter 0
  f32x4 rawA[8];
  {
    const float* p0 = pair + (size_t)(row0 + t16) * CC + g*8;
    #pragma unroll
    for (int kc = 0; kc < 4; ++kc) {
      rawA[kc*2]     = *(const f32x4*)(p0 + kc*32);
      rawA[kc*2 + 1] = *(const f32x4*)(p0 + kc*32 + 4);
    }
  }

  #pragma unroll
  for (int mc = 0; mc < 4; ++mc) {
    const int m = row0 + mc*16 + t16;
    f32x4 rawB[8];
    if (mc < 3) {   // issue next-iter loads before this iter's compute
      const float* pn = pair + (size_t)(m + 16) * CC + g*8;
      #pragma unroll
      for (int kc = 0; kc < 4; ++kc) {
        rawB[kc*2]     = *(const f32x4*)(pn + kc*32);
        rawB[kc*2 + 1] = *(const f32x4*)(pn + kc*32 + 4);
      }
    }

    bf16x8 pf[4];
    #pragma unroll
    for (int kc = 0; kc < 4; ++kc) {
      bf16x8 a;
      #pragma unroll
      for (int j = 0; j < 8; ++j) a[j] = f2bf(rawA[kc*2 + (j>>2)][j&3]);
      pf[kc] = a;
    }

    f32x4 acc[8];
    #pragma unroll
    for (int nt = 0; nt < 8; ++nt) acc[nt] = f32x4{0.f,0.f,0.f,0.f};
    #pragma unroll
    for (int kc = 0; kc < 4; ++kc)
      #pragma unroll
      for (int nt = 0; nt < 8; ++nt)
        acc[nt] = __builtin_amdgcn_mfma_f32_16x16x32_bf16(wf[nt][kc], pf[kc], acc[nt], 0, 0, 0);

    // D[n][m]: lane owns cols nt*16+g*4+r of row m -> packed 8B stores, [m][C]
    const size_t rowoff = (size_t)m * CC;
    #pragma unroll
    for (int nt = 0; nt < 8; ++nt) {
      f32x4 v;
      #pragma unroll
      for (int r = 0; r < 4; ++r) v[r] = acc[nt][r] + bcol[nt][r];
      if (wid == 3) {
        #pragma unroll
        for (int r = 0; r < 4; ++r) v[r] = 1.f / (1.f + __expf(-v[r]));
      }
      bf16x4 pk;
      #pragma unroll
      for (int r = 0; r < 4; ++r) pk[r] = f2bf(v[r]);
      *(bf16x4*)(outp + rowoff + nt*16 + g*4) = pk;
    }

    if (mc < 3) {
      #pragma unroll
      for (int u = 0; u < 8; ++u) rawA[u] = rawB[u];
    }
  }
}

// ---------------- Kernel B: per-(i,h) attention, K from L2, 32KB LDS ------------
// grid 1024 (i*4+h), block 256 (4 waves); wave = 64 q-rows in 4 chunks of 16.
// QK^T swapped (lane owns q-row t16's 64 scores); PV swapped via swizzled V^T/P LDS.
// Layouts all [m][C] bf16 (m = i*256+j, C = h*32+ch). HW-verified core (round 9).
// ao aliases qi: each wave reads its Q rows before writing those rows' ao bytes;
// cross-block, (i,h) writes exactly the bytes only it reads.
__global__ __launch_bounds__(256) void attn_kernel(
    const short* __restrict__ qi, const short* __restrict__ ki,
    const short* __restrict__ vi, short* __restrict__ ao)
{
  __shared__ short Vsl[32*256];    // [ch][kpos] swizzled: idx = ch*256 + (kp ^ ((ch&7)<<3))
  __shared__ short Pl[4][2048];    // per-wave [16 q][128 kp-half]: q*128 + (kp_l ^ ((q&7)<<3))

  const int bid  = blockIdx.x;
  const int i    = bid >> 2, h = bid & 3;
  const int tid  = threadIdx.x;
  const int wid  = tid >> 6, lane = tid & 63;
  const int g    = lane >> 4, t16 = lane & 15;
  const size_t mbase = (size_t)i * NN;    // row index base

  { // stage V^T (kpos = tid), scalar scatter with swizzle
    const short* vr = vi + (mbase + tid) * CC + h*32;
    #pragma unroll
    for (int u = 0; u < 4; ++u) {
      bf16x8 v8 = *(const bf16x8*)(vr + u*8);
      #pragma unroll
      for (int e = 0; e < 8; ++e) {
        const int ch = u*8 + e;
        Vsl[ch*256 + (tid ^ ((ch & 7) << 3))] = v8[e];
      }
    }
  }
  __syncthreads();

  const float cs = 0.17677669529663689f * 1.4426950408889634f; // scale * log2(e)
  const int swzP = (t16 & 7) << 3;
  const int ch0 = t16, ch1 = 16 + t16;                   // ch within head (0..31)
  const int swzV0 = (ch0 & 7) << 3, swzV1 = (ch1 & 7) << 3;
  short* Pw = &Pl[wid][0];

  #pragma unroll 1
  for (int cc = 0; cc < 4; ++cc) {
    const int q0 = wid*64 + cc*16;
    bf16x8 qf = *(const bf16x8*)(qi + (mbase + q0 + t16)*CC + h*32 + g*8);

    f32x4 s[16];
    #pragma unroll
    for (int t = 0; t < 16; ++t) {
      bf16x8 kf = *(const bf16x8*)(ki + (mbase + t*16 + t16)*CC + h*32 + g*8);
      s[t] = __builtin_amdgcn_mfma_f32_16x16x32_bf16(kf, qf, f32x4{0.f,0.f,0.f,0.f}, 0, 0, 0);
    }

    // softmax for q-row q0+t16: in-lane over 64 scores + reduce across g
    f32x4 m4 = s[0];
    #pragma unroll
    for (int t = 1; t < 16; ++t)
      #pragma unroll
      for (int r = 0; r < 4; ++r) m4[r] = fmaxf(m4[r], s[t][r]);
    float mx = fmaxf(fmaxf(m4[0], m4[1]), fmaxf(m4[2], m4[3]));
    mx = fmaxf(mx, __shfl_xor(mx, 16));
    mx = fmaxf(mx, __shfl_xor(mx, 32));

    f32x4 s4 = f32x4{0.f,0.f,0.f,0.f};
    #pragma unroll
    for (int t = 0; t < 16; ++t) {
      f32x4 v = s[t];
      #pragma unroll
      for (int r = 0; r < 4; ++r) { v[r] = exp2f((v[r] - mx) * cs); s4[r] += v[r]; }
      s[t] = v;
    }
    float sum = (s4[0] + s4[1]) + (s4[2] + s4[3]);
    sum += __shfl_xor(sum, 16);
    sum += __shfl_xor(sum, 32);
    const float sm = 1.f / sum;

    f32x4 o0 = f32x4{0.f,0.f,0.f,0.f};
    f32x4 o1 = f32x4{0.f,0.f,0.f,0.f};
    #pragma unroll
    for (int half = 0; half < 2; ++half) {
      asm volatile("s_waitcnt lgkmcnt(0)" ::: "memory"); // WAR vs prev P reads
      #pragma unroll
      for (int tt = 0; tt < 8; ++tt) {
        const int t = half*8 + tt;
        bf16x4 pk;
        #pragma unroll
        for (int r = 0; r < 4; ++r) pk[r] = f2bf(s[t][r]);
        *(bf16x4*)&Pw[t16*128 + ((tt*16 + g*4) ^ swzP)] = pk;
      }
      asm volatile("s_waitcnt lgkmcnt(0)" ::: "memory"); // writes land before reads

      bf16x8 pa[4];
      #pragma unroll
      for (int kc = 0; kc < 4; ++kc)
        pa[kc] = *(const bf16x8*)&Pw[t16*128 + ((kc*32 + g*8) ^ swzP)];

      #pragma unroll
      for (int kc = 0; kc < 4; ++kc) {
        const int kb = half*128 + kc*32 + g*8;
        bf16x8 v0 = *(const bf16x8*)&Vsl[ch0*256 + (kb ^ swzV0)];
        bf16x8 v1 = *(const bf16x8*)&Vsl[ch1*256 + (kb ^ swzV1)];
        o0 = __builtin_amdgcn_mfma_f32_16x16x32_bf16(v0, pa[kc], o0, 0, 0, 0);
        o1 = __builtin_amdgcn_mfma_f32_16x16x32_bf16(v1, pa[kc], o1, 0, 0, 0);
      }
    }

    // D[ch][q]: lane owns 4 consecutive ch of its own q-row
    const size_t ob = (mbase + q0 + t16)*CC + h*32;
    bf16x4 pk0, pk1;
    #pragma unroll
    for (int r = 0; r < 4; ++r) { pk0[r] = f2bf(o0[r] * sm); pk1[r] = f2bf(o1[r] * sm); }
    *(bf16x4*)(ao + ob + g*4)      = pk0;
    *(bf16x4*)(ao + ob + 16 + g*4) = pk1;
  }
}

// ---------------- Kernel C: gate*attn @ Wo^T + residual + LayerNorm -------------
// grid 1024 (64 rows), block 256 (4 waves, wave = 16 rows). ai/gi loads issued
// before the Wl-staging barrier to overlap.
__global__ __launch_bounds__(256) void out_kernel(
    const short* __restrict__ ai, const short* __restrict__ gi,
    const short* __restrict__ wpk_o, const float* __restrict__ bo,
    const float* __restrict__ pair, const float* __restrict__ gamma,
    const float* __restrict__ beta, float* __restrict__ out)
{
  __shared__ short Wl[16384];
  const int tid = threadIdx.x;
  const int wid = tid >> 6, lane = tid & 63;
  const int g = lane >> 4, t16 = lane & 15;

  const int m0 = blockIdx.x*64 + wid*16;
  const size_t rowoff = (size_t)(m0 + t16) * CC;

  // issue global loads first (overlap with LDS staging)
  bf16x8 a8[4], g8[4];
  #pragma unroll
  for (int kc = 0; kc < 4; ++kc) {
    a8[kc] = *(const bf16x8*)(ai + rowoff + kc*32 + g*8);
    g8[kc] = *(const bf16x8*)(gi + rowoff + kc*32 + g*8);
  }

  #pragma unroll
  for (int it = 0; it < 8; ++it) {   // stage prepacked Wo -> LDS, coalesced
    const int c = it*256 + tid;
    *(bf16x8*)&Wl[c*8] = *(const bf16x8*)(wpk_o + (size_t)c*8);
  }
  __syncthreads();

  bf16x8 xf[4];
  #pragma unroll
  for (int kc = 0; kc < 4; ++kc) {
    bf16x8 o;
    #pragma unroll
    for (int j = 0; j < 8; ++j) o[j] = f2bf(bf2f(a8[kc][j]) * bf2f(g8[kc][j]));
    xf[kc] = o;
  }

  f32x4 acc[8];
  #pragma unroll
  for (int nt = 0; nt < 8; ++nt) acc[nt] = f32x4{0.f,0.f,0.f,0.f};
  #pragma unroll
  for (int kc = 0; kc < 4; ++kc)
    #pragma unroll
    for (int nt = 0; nt < 8; ++nt) {
      bf16x8 wfr = *(const bf16x8*)&Wl[((nt*4 + kc)*64 + lane)*8];
      acc[nt] = __builtin_amdgcn_mfma_f32_16x16x32_bf16(wfr, xf[kc], acc[nt], 0, 0, 0);
    }

  float val[8][4];
  #pragma unroll
  for (int nt = 0; nt < 8; ++nt) {
    f32x4 b4 = *(const f32x4*)(bo + nt*16 + g*4);
    f32x4 p4 = *(const f32x4*)(pair + rowoff + nt*16 + g*4);
    #pragma unroll
    for (int r = 0; r < 4; ++r) val[nt][r] = acc[nt][r] + b4[r] + p4[r];
  }
  float sum = 0.f;
  #pragma unroll
  for (int nt = 0; nt < 8; ++nt)
    #pragma unroll
    for (int r = 0; r < 4; ++r) sum += val[nt][r];
  sum += __shfl_xor(sum, 16); sum += __shfl_xor(sum, 32);
  const float mu = sum * (1.f/128.f);
  float sq = 0.f;
  #pragma unroll
  for (int nt = 0; nt < 8; ++nt)
    #pragma unroll
    for (int r = 0; r < 4; ++r) { float d = val[nt][r] - mu; sq += d*d; }
  sq += __shfl_xor(sq, 16); sq += __shfl_xor(sq, 32);
  const float rstd = rsqrtf(sq * (1.f/128.f) + 1e-5f);

  #pragma unroll
  for (int nt = 0; nt < 8; ++nt) {
    f32x4 g4 = *(const f32x4*)(gamma + nt*16 + g*4);
    f32x4 b4 = *(const f32x4*)(beta  + nt*16 + g*4);
    f32x4 o4;
    #pragma unroll
    for (int r = 0; r < 4; ++r) o4[r] = (val[nt][r] - mu) * rstd * g4[r] + b4[r];
    *(f32x4*)(out + rowoff + nt*16 + g*4) = o4;
  }
}

extern "C" void kernel_launch(void* const* d_in, const int* in_sizes, int n_in,
                              void* d_out, int out_size, void* d_ws, size_t ws_size,
                              hipStream_t stream) {
  const float* pair  = (const float*)d_in[0];
  const float* Wq    = (const float*)d_in[1];
  const float* bq    = (const float*)d_in[2];
  const float* Wk    = (const float*)d_in[3];
  const float* bk    = (const float*)d_in[4];
  const float* Wv    = (const float*)d_in[5];
  const float* bv    = (const float*)d_in[6];
  const float* Wg    = (const float*)d_in[7];
  const float* bg    = (const float*)d_in[8];
  const float* Wo    = (const float*)d_in[9];
  const float* bo    = (const float*)d_in[10];
  const float* gamma = (const float*)d_in[11];
  const float* beta  = (const float*)d_in[12];
  float* out = (float*)d_out;

  short* wpk  = (short*)d_ws;            // 5 * 16384 bf16, prepacked weights
  short* q_ws = wpk + 81920;             // [m][C] bf16
  short* k_ws = q_ws + 8388608;
  short* v_ws = k_ws + 8388608;
  short* g_ws = v_ws + 8388608;          // [m][C] bf16 (sigmoid applied)
  short* a_ws = q_ws;                    // attn out aliases Q (proven-safe, see attn)

  hipLaunchKernelGGL(prep_kernel, dim3(40), dim3(256), 0, stream,
                     Wq, Wk, Wv, Wg, Wo, wpk);
  hipLaunchKernelGGL(proj_kernel, dim3(1024), dim3(256), 0, stream,
                     pair, wpk, bq, bk, bv, bg, q_ws, k_ws, v_ws, g_ws);
  hipLaunchKernelGGL(attn_kernel, dim3(1024), dim3(256), 0, stream,
                     q_ws, k_ws, v_ws, a_ws);
  hipLaunchKernelGGL(out_kernel, dim3(1024), dim3(256), 0, stream,
                     a_ws, g_ws, wpk + 4*16384, bo, pair, gamma, beta, out);
}